// Round 3
// baseline (130.170 us; speedup 1.0000x reference)
//
#include <hip/hip_runtime.h>
#include <hip/hip_bf16.h>

#define NB 4
#define NN 4096

typedef short  bf16x8 __attribute__((ext_vector_type(8)));
typedef float  f32x4  __attribute__((ext_vector_type(4)));

static __device__ __forceinline__ ushort f2bf(float f) {
    unsigned u = __float_as_uint(f);
    u += 0x7fffu + ((u >> 16) & 1u);
    return (ushort)(u >> 16);
}

// pack two f32 -> one dword of 2x bf16 (lo = a, hi = b), RNE — matches f2bf
static __device__ __forceinline__ unsigned cvt_pk_bf16(float a, float b) {
    unsigned r;
    asm("v_cvt_pk_bf16_f32 %0, %1, %2" : "=v"(r) : "v"(a), "v"(b));
    return r;
}

// ================= fused conv1 + conv2 + qkv =================
// One block per (h, b). Phase 1: conv1 for rows h-1..h+1 (x -> y1 in regs),
// recomputed per block (3x conv1 MFMA work, but conv1 is tiny). Phase 2:
// conv2 from reg-held y1. Phase 3: qkv projections. LDS phases share a
// 63,744 B union. 512 threads = 8 waves.
__global__ __launch_bounds__(512) void conv12qkv(
    const float* __restrict__ x,  const float* __restrict__ w1,
    const float* __restrict__ g1, const float* __restrict__ b1,
    const float* __restrict__ m1, const float* __restrict__ v1,
    const float* __restrict__ w2,
    const float* __restrict__ g2, const float* __restrict__ b2,
    const float* __restrict__ m2, const float* __restrict__ v2,
    const float* __restrict__ qw, const float* __restrict__ qb,
    const float* __restrict__ kw, const float* __restrict__ kb,
    const float* __restrict__ vw, const float* __restrict__ vb,
    float* __restrict__ y, ushort* __restrict__ q8,
    ushort* __restrict__ ko, ushort* __restrict__ vt)
{
    __shared__ __align__(16) ushort LDSU[31872];     // 63,744 B
    ushort* As1 = LDSU;            // [32][600]            (phase 1)
    ushort* Xs1 = LDSU + 19200;    // [24][66][8]          (phase 1)
    ushort* As2 = LDSU;            // [64][312]            (phase 2)
    ushort* Xs2 = LDSU + 19968;    // [12][66][8]          (phase 2)
    ushort* Yt  = LDSU + 26304;    // [64][76]             (phase 2-3)
    float*  Bv  = (float*)(LDSU + 31168);  // [80]         (phase 3)
    ushort* Wq  = LDSU;            // [80][76]             (phase 3, over As2)

    const int tid = threadIdx.x;
    const int h = blockIdx.x, b = blockIdx.y;

    const int lane = tid & 63, wv = tid >> 6;     // wv 0..7
    const int quad = lane >> 4, l15 = lane & 15;

    // ---------------- phase 1: conv1 rows h-1..h+1 ----------------
    // stage W1 (f32 -> bf16, reordered): As1[co][tap*64 + ci]
    for (int cid = tid; cid < 2304; cid += 512) {
        const int row = cid / 72, off = cid % 72;
        const int k0 = off * 8;
        const int tap = k0 >> 6, ci0 = k0 & 63;
        float v[8];
        #pragma unroll
        for (int j = 0; j < 8; ++j)
            v[j] = w1[((size_t)(row * 64 + ci0 + j)) * 9 + tap];
        union { unsigned u[4]; uint4 q; } pk;
        #pragma unroll
        for (int j = 0; j < 4; ++j) pk.u[j] = cvt_pk_bf16(v[2*j], v[2*j+1]);
        *(uint4*)&As1[row * 600 + off * 8] = pk.q;
    }

    // conv1 thread geometry
    const int ch = wv & 1, ph2 = wv >> 1;         // co half, pixel 16-group
    const int p1 = ph2 * 16 + l15;                // conv1 output pixel
    const int cb1 = ch * 16 + quad * 4;           // conv1 co base
    float sc1[4], bs1[4];
    #pragma unroll
    for (int r = 0; r < 4; ++r) {
        int co = cb1 + r;
        sc1[r] = g1[co] / sqrtf(v1[co] + 1e-5f);
        bs1[r] = b1[co] - m1[co] * sc1[r];
    }

    uint2 yreg[3];
    const int snn = tid & 63, scc = tid >> 6;     // staging split
    #pragma unroll
    for (int r1 = 0; r1 < 3; ++r1) {
        const int gh1 = h - 1 + r1;               // conv1 output row
        // stage x rows gh1-1..gh1+1 channel-last into Xs1
        #pragma unroll
        for (int r = 0; r < 3; ++r) {
            const int gh = gh1 - 1 + r;
            float v[8];
            if ((unsigned)gh < 64u) {
                #pragma unroll
                for (int sub = 0; sub < 8; ++sub)
                    v[sub] = x[(((size_t)b * 64 + scc * 8 + sub) * 64 + gh) * 64 + snn];
            } else {
                #pragma unroll
                for (int sub = 0; sub < 8; ++sub) v[sub] = 0.f;
            }
            union { unsigned u[4]; uint4 q; } pk;
            #pragma unroll
            for (int j = 0; j < 4; ++j) pk.u[j] = cvt_pk_bf16(v[2*j], v[2*j+1]);
            *(uint4*)&Xs1[((r * 8 + scc) * 66 + (snn + 1)) * 8] = pk.q;
        }
        if (tid < 48) {
            int r = tid >> 4, q = tid & 15, cc = q >> 1, side = (q & 1) * 65;
            uint4 z = {0, 0, 0, 0};
            *(uint4*)&Xs1[((r * 8 + cc) * 66 + side) * 8] = z;
        }
        __syncthreads();

        if ((unsigned)gh1 < 64u) {
            f32x4 acc = {0.f, 0.f, 0.f, 0.f};
            #pragma unroll
            for (int kk = 0; kk < 18; ++kk) {
                const int tap = kk >> 1;
                const int dyr = tap / 3, dx = tap % 3;
                bf16x8 af = *(const bf16x8*)&As1[(ch * 16 + l15) * 600 + kk * 32 + quad * 8];
                bf16x8 bf = *(const bf16x8*)&Xs1[((dyr * 8 + (kk & 1) * 4 + quad) * 66 + p1 + dx) * 8];
                acc = __builtin_amdgcn_mfma_f32_16x16x32_bf16(af, bf, acc, 0, 0, 0);
            }
            float r_[4];
            #pragma unroll
            for (int r = 0; r < 4; ++r) {
                float pre = acc[r] * sc1[r] + bs1[r];
                r_[r] = pre / (1.f + __expf(-pre));
            }
            yreg[r1].x = cvt_pk_bf16(r_[0], r_[1]);
            yreg[r1].y = cvt_pk_bf16(r_[2], r_[3]);
        } else {
            yreg[r1].x = 0u; yreg[r1].y = 0u;
        }
        __syncthreads();   // Xs1 (and, after r1==2, As1) free for reuse
    }

    // ---------------- phase 2: conv2 ----------------
    // stage W2 -> As2[co][tap*32 + ci]
    for (int cid = tid; cid < 2304; cid += 512) {
        const int row = cid / 36, off = cid % 36;
        const int k0 = off * 8;
        const int tap = k0 >> 5, ci0 = k0 & 31;
        float v[8];
        #pragma unroll
        for (int j = 0; j < 8; ++j)
            v[j] = w2[((size_t)(row * 32 + ci0 + j)) * 9 + tap];
        union { unsigned u[4]; uint4 q; } pk;
        #pragma unroll
        for (int j = 0; j < 4; ++j) pk.u[j] = cvt_pk_bf16(v[2*j], v[2*j+1]);
        *(uint4*)&As2[row * 312 + off * 8] = pk.q;
    }
    // y1 regs -> Xs2 channel-last: row r1, pixel p1, channels cb1..cb1+3
    #pragma unroll
    for (int r1 = 0; r1 < 3; ++r1)
        *(uint2*)&Xs2[((r1 * 4 + (cb1 >> 3)) * 66 + (p1 + 1)) * 8 + (cb1 & 7)] = yreg[r1];
    if (tid < 24) {
        int r = tid >> 3, q = tid & 7, cc = q >> 1, side = (q & 1) * 65;
        uint4 z = {0, 0, 0, 0};
        *(uint4*)&Xs2[((r * 4 + cc) * 66 + side) * 8] = z;
    }
    __syncthreads();

    const int ct2 = wv & 3, phh = wv >> 2;        // co tile, pixel 32-half
    f32x4 acc2[2] = {{0.f,0.f,0.f,0.f},{0.f,0.f,0.f,0.f}};
    #pragma unroll
    for (int kk = 0; kk < 9; ++kk) {
        const int dyr = kk / 3, dx = kk % 3;
        bf16x8 af = *(const bf16x8*)&As2[(ct2 * 16 + l15) * 312 + kk * 32 + quad * 8];
        #pragma unroll
        for (int s = 0; s < 2; ++s) {
            int p = phh * 32 + s * 16 + l15;
            bf16x8 bf = *(const bf16x8*)&Xs2[((dyr * 4 + quad) * 66 + p + dx) * 8];
            acc2[s] = __builtin_amdgcn_mfma_f32_16x16x32_bf16(af, bf, acc2[s], 0, 0, 0);
        }
    }

    const int cb2 = ct2 * 16 + quad * 4;
    float sc2[4], bs2[4];
    #pragma unroll
    for (int r = 0; r < 4; ++r) {
        int co = cb2 + r;
        sc2[r] = g2[co] / sqrtf(v2[co] + 1e-5f);
        bs2[r] = b2[co] - m2[co] * sc2[r];
    }
    #pragma unroll
    for (int s = 0; s < 2; ++s) {
        int p = phh * 32 + s * 16 + l15;
        #pragma unroll
        for (int r = 0; r < 4; ++r) {
            float pre = acc2[s][r] * sc2[r] + bs2[r];
            float res = pre / (1.f + __expf(-pre));
            y[((size_t)(b * 64 + cb2 + r)) * NN + h * 64 + p] = res;
            Yt[p * 76 + cb2 + r] = f2bf(res);
        }
    }
    __syncthreads();   // Yt complete; As2 reads done

    // ---------------- phase 3: qkv ----------------
    for (int i = tid; i < 2560; i += 512) {
        int chw = i >> 5, c2 = (i & 31) * 2;
        const float* src = (chw < 8) ? (qw + chw * 64 + c2)
                         : (chw < 16) ? (kw + (chw - 8) * 64 + c2)
                         : (vw + (chw - 16) * 64 + c2);
        float2 v2_ = *(const float2*)src;
        *(unsigned*)&Wq[chw * 76 + c2] = cvt_pk_bf16(v2_.x, v2_.y);
    }
    if (tid < 80) Bv[tid] = (tid < 8) ? qb[tid] : (tid < 16) ? kb[tid - 8] : vb[tid - 16];
    __syncthreads();

    // waves 0-3 do cht 0..2 (q,k + v low), waves 4-7 do cht 3..4
    const int pg = wv & 3;
    bf16x8 aY0 = *(const bf16x8*)&Yt[(pg * 16 + l15) * 76 + quad * 8];
    bf16x8 aY1 = *(const bf16x8*)&Yt[(pg * 16 + l15) * 76 + 32 + quad * 8];
    const int nbase = h * 64 + pg * 16 + quad * 4;
    const int vtile = h * 2 + (pg >> 1);
    const int vslot = quad * 8 + (pg & 1) * 4;
    const int cht0 = (wv < 4) ? 0 : 3;
    const int chtN = (wv < 4) ? 3 : 5;
    for (int cht = cht0; cht < chtN; ++cht) {
        bf16x8 bW0 = *(const bf16x8*)&Wq[(cht * 16 + l15) * 76 + quad * 8];
        bf16x8 bW1 = *(const bf16x8*)&Wq[(cht * 16 + l15) * 76 + 32 + quad * 8];
        f32x4 qa = {0.f, 0.f, 0.f, 0.f};
        qa = __builtin_amdgcn_mfma_f32_16x16x32_bf16(aY0, bW0, qa, 0, 0, 0);
        qa = __builtin_amdgcn_mfma_f32_16x16x32_bf16(aY1, bW1, qa, 0, 0, 0);
        const float bias = Bv[cht * 16 + l15];
        const int chn = cht * 16 + l15;
        if (cht == 0) {
            if (l15 < 8) {
                #pragma unroll
                for (int r = 0; r < 4; ++r)
                    q8[((size_t)b * NN + nbase + r) * 8 + chn] = f2bf(qa[r] + bias);
            } else {
                #pragma unroll
                for (int r = 0; r < 4; ++r)
                    ko[((size_t)b * NN + nbase + r) * 8 + (chn - 8)] = f2bf(qa[r] + bias);
            }
        } else {
            const int c = chn - 16;
            uint2 st;
            st.x = cvt_pk_bf16(qa[0] + bias, qa[1] + bias);
            st.y = cvt_pk_bf16(qa[2] + bias, qa[3] + bias);
            *(uint2*)&vt[(((size_t)(b * 128 + vtile)) * 64 + c) * 32 + vslot] = st;
        }
    }
}

// ---------------- flash PAM v9: 64 queries/block ----------------
// grid 256 (4b x 64nt), 512 threads; zero loop barriers.
__global__ __launch_bounds__(512, 2) void flash_pam(
    const ushort* __restrict__ q8,
    const ushort* __restrict__ k8,
    const ushort* __restrict__ vt,
    const float* __restrict__ y,
    const float* __restrict__ x,
    const float* __restrict__ gamma_p,
    float* __restrict__ out)
{
    __shared__ __align__(16) float Osum[4 * 4352];   // [slot][c:64 stride 68][n:64]
    __shared__ float Lw[8][64];
    __shared__ float Ls[64];

    const int tid = threadIdx.x;
    const int bx = blockIdx.x;
    const int b  = bx >> 6;
    const int nt = bx & 63;
    const int n0 = nt * 64;

    const int lane = tid & 63, w = tid >> 6;   // w in 0..7
    const int quad = lane >> 4, l15 = lane & 15;

    const uint4 z4 = {0u, 0u, 0u, 0u};

    // Q B-frags: row n = l15 (+16*af), k = d at quad 0; zero pad elsewhere.
    bf16x8 bQ[4];
    #pragma unroll
    for (int af = 0; af < 4; ++af) {
        uint4 qv = *(const uint4*)(q8 + ((size_t)b * NN + n0 + af * 16 + l15) * 8);
        uint4 sel = (quad == 0) ? qv : z4;
        bQ[af] = *(bf16x8*)&sel;
    }

    const ushort* kg = k8 + ((size_t)b * NN + w * 512) * 8;
    const ushort* vg = vt + ((size_t)(b * 128 + w * 16)) * 64 * 32;

    f32x4 acc[4][4];
    #pragma unroll
    for (int af = 0; af < 4; ++af)
        #pragma unroll
        for (int ct = 0; ct < 4; ++ct)
            acc[af][ct] = (f32x4){0.f, 0.f, 0.f, 0.f};
    float lacc[4] = {0.f, 0.f, 0.f, 0.f};
    const f32x4 zf = {0.f, 0.f, 0.f, 0.f};

    #pragma unroll 2
    for (int t = 0; t < 16; ++t) {
        const int g = t * 32;
        bf16x8 aK0 = *(const bf16x8*)(kg + (size_t)(g + l15) * 8);
        bf16x8 aK1 = *(const bf16x8*)(kg + (size_t)(g + 16 + l15) * 8);

        bf16x8 vb_[4];
        #pragma unroll
        for (int ct = 0; ct < 4; ++ct)
            vb_[ct] = *(const bf16x8*)(vg + (size_t)t * 2048 + (ct * 16 + l15) * 32 + quad * 8);

        #pragma unroll
        for (int af = 0; af < 4; ++af) {
            f32x4 s0 = __builtin_amdgcn_mfma_f32_16x16x32_bf16(aK0, bQ[af], zf, 0, 0, 0);
            f32x4 s1 = __builtin_amdgcn_mfma_f32_16x16x32_bf16(aK1, bQ[af], zf, 0, 0, 0);

            float e[8];
            #pragma unroll
            for (int r = 0; r < 4; ++r) {
                e[r]     = __expf(s0[r]);
                e[4 + r] = __expf(s1[r]);
            }
            #pragma unroll
            for (int r = 0; r < 8; ++r) lacc[af] += e[r];
            union { unsigned u[4]; bf16x8 v; } pk;
            pk.u[0] = cvt_pk_bf16(e[0], e[1]);
            pk.u[1] = cvt_pk_bf16(e[2], e[3]);
            pk.u[2] = cvt_pk_bf16(e[4], e[5]);
            pk.u[3] = cvt_pk_bf16(e[6], e[7]);

            #pragma unroll
            for (int ct = 0; ct < 4; ++ct)
                acc[af][ct] = __builtin_amdgcn_mfma_f32_16x16x32_bf16(pk.v, vb_[ct], acc[af][ct], 0, 0, 0);
        }
    }

    #pragma unroll
    for (int af = 0; af < 4; ++af) {
        lacc[af] += __shfl_xor(lacc[af], 16, 64);
        lacc[af] += __shfl_xor(lacc[af], 32, 64);
    }
    if (quad == 0) {
        #pragma unroll
        for (int af = 0; af < 4; ++af)
            Lw[w][af * 16 + l15] = lacc[af];
    }

    if (w >= 4) {
        #pragma unroll
        for (int af = 0; af < 4; ++af)
            #pragma unroll
            for (int ct = 0; ct < 4; ++ct)
                *(f32x4*)&Osum[(w - 4) * 4352 + (ct * 16 + l15) * 68 + af * 16 + quad * 4] = acc[af][ct];
    }
    __syncthreads();
    if (w < 4) {
        #pragma unroll
        for (int af = 0; af < 4; ++af)
            #pragma unroll
            for (int ct = 0; ct < 4; ++ct) {
                float* p = &Osum[w * 4352 + (ct * 16 + l15) * 68 + af * 16 + quad * 4];
                f32x4 v = *(const f32x4*)p;
                *(f32x4*)p = v + acc[af][ct];
            }
    }
    if (tid < 64) {
        float s = Lw[0][tid] + Lw[1][tid] + Lw[2][tid] + Lw[3][tid]
                + Lw[4][tid] + Lw[5][tid] + Lw[6][tid] + Lw[7][tid];
        Ls[tid] = 1.0f / s;
    }
    __syncthreads();

    {
        const int c = tid >> 3, n8 = (tid & 7) * 8;
        f32x4 o0 = {0.f, 0.f, 0.f, 0.f}, o1 = {0.f, 0.f, 0.f, 0.f};
        #pragma unroll
        for (int s = 0; s < 4; ++s) {
            o0 += *(const f32x4*)&Osum[s * 4352 + c * 68 + n8];
            o1 += *(const f32x4*)&Osum[s * 4352 + c * 68 + n8 + 4];
        }
        const float g2 = 2.f * gamma_p[0];
        const size_t idx = ((size_t)b * 64 + c) * NN + n0 + n8;
        f32x4 xv0 = *(const f32x4*)(x + idx);
        f32x4 xv1 = *(const f32x4*)(x + idx + 4);
        f32x4 yv0 = *(const f32x4*)(y + idx);
        f32x4 yv1 = *(const f32x4*)(y + idx + 4);
        f32x4 r0, r1;
        #pragma unroll
        for (int u = 0; u < 4; ++u) {
            r0[u] = xv0[u] + 2.f * yv0[u] + g2 * o0[u] * Ls[n8 + u];
            r1[u] = xv1[u] + 2.f * yv1[u] + g2 * o1[u] * Ls[n8 + 4 + u];
        }
        *(f32x4*)(out + idx) = r0;
        *(f32x4*)(out + idx + 4) = r1;
    }
}

extern "C" void kernel_launch(void* const* d_in, const int* in_sizes, int n_in,
                              void* d_out, int out_size, void* d_ws, size_t ws_size,
                              hipStream_t stream) {
    const float* x    = (const float*)d_in[0];
    const float* w1   = (const float*)d_in[1];
    const float* g1   = (const float*)d_in[2];
    const float* b1   = (const float*)d_in[3];
    const float* m1   = (const float*)d_in[4];
    const float* v1   = (const float*)d_in[5];
    const float* w2   = (const float*)d_in[6];
    const float* g2   = (const float*)d_in[7];
    const float* b2   = (const float*)d_in[8];
    const float* m2   = (const float*)d_in[9];
    const float* v2   = (const float*)d_in[10];
    const float* qw   = (const float*)d_in[11];
    const float* qb   = (const float*)d_in[12];
    const float* kw   = (const float*)d_in[13];
    const float* kb   = (const float*)d_in[14];
    const float* vw   = (const float*)d_in[15];
    const float* vb   = (const float*)d_in[16];
    const float* gam  = (const float*)d_in[17];
    float* outp = (float*)d_out;

    float* ws = (float*)d_ws;
    float*  y   = ws + 524288;                 // 1,048,576 f
    ushort* q8  = (ushort*)(ws + 1572864);     // 131,072 ush bf16
    ushort* kk  = (ushort*)(ws + 1703936);     // 131,072 ush bf16
    ushort* vv  = (ushort*)(ws + 1769472);     // 1,048,576 ush bf16 (blocked layout)

    conv12qkv<<<dim3(64, NB), 512, 0, stream>>>(x, w1, g1, b1, m1, v1,
                                                w2, g2, b2, m2, v2,
                                                qw, qb, kw, kb, vw, vb,
                                                y, q8, kk, vv);
    flash_pam<<<256, 512, 0, stream>>>(q8, kk, vv, y, x, gam, outp);
}